// Round 9
// baseline (337.013 us; speedup 1.0000x reference)
//
#include <hip/hip_runtime.h>
#include <math.h>

typedef unsigned short u16;
typedef __attribute__((ext_vector_type(8))) short short8;
typedef __attribute__((ext_vector_type(4))) float f32x4;
typedef __attribute__((ext_vector_type(4))) int   i32x4;

// Problem constants (B=8, N=2048, Nsrc=2048, C=512, H=W=64, sr_ratio=2 -> 32x32 grid)
#define BB     8
#define NN     2048
#define CC     512
#define HEADS  8
#define HD     64
#define GM     1024   // 32*32 spatial tokens per batch

#define LOG2E     1.44269504088896340736f
#define QSCALE    (0.125f * LOG2E)

// Workspace byte offsets (total ~82.6 MB)
#define B_FEATF   ((size_t)0)                    // slots int[8192*128] 4MB; later attn_bf 16MB
#define B_XSF     ((size_t)16*1024*1024)         // xs fp32 16MB; later q_bf 16MB
#define B_XBF     ((size_t)32*1024*1024)         // x bf16 16MB
#define B_KB      ((size_t)48*1024*1024)         // K fragments bf16 [bh][kt][ks][jt][lane][8] 8MB
#define B_VT      ((size_t)56*1024*1024)         // V^T bf16 [b][h][64][1024] 8MB (key-permuted)
#define B_FEATBF  ((size_t)64*1024*1024)         // feat bf16 8MB
#define B_XSBF    ((size_t)72*1024*1024)         // xs bf16 8MB
#define B_CNT     ((size_t)80*1024*1024)         // cnt int[8192] 32KB
#define B_CONF    (B_CNT + (size_t)32*1024)      // conf float[8192] 32KB (pre-scaled by log2e)
#define B_WQ      (B_CNT + (size_t)64*1024)      // 512KB
#define B_WKV     (B_WQ  + (size_t)512*1024)     // 1MB
#define B_WSR     (B_WKV + (size_t)1024*1024)    // 512KB
#define B_WPROJ   (B_WSR + (size_t)512*1024)     // 512KB

__device__ __forceinline__ u16 f2bf(float f) {
    unsigned u = __float_as_uint(f);
    unsigned r = (u + 0x7fffu + ((u >> 16) & 1u)) >> 16;   // RNE
    return (u16)r;
}

__device__ __forceinline__ unsigned cvt_pk_bf16(float lo, float hi) {
    unsigned r;
    asm("v_cvt_pk_bf16_f32 %0, %1, %2" : "=v"(r) : "v"(lo), "v"(hi));
    return r;
}

// ---------------------------------------------------------------------------
// all fp32->bf16 casts in ONE launch (segmented grid; each block = 256 float4)
// ---------------------------------------------------------------------------
__global__ __launch_bounds__(256) void cast_all_kernel(
    const float* __restrict__ x,      u16* __restrict__ x_bf,
    const float* __restrict__ q_w,    u16* __restrict__ wq_bf,
    const float* __restrict__ kv_w,   u16* __restrict__ wkv_bf,
    const float* __restrict__ sr_w,   u16* __restrict__ wsr_bf,
    const float* __restrict__ proj_w, u16* __restrict__ wpr_bf)
{
    const int bid = blockIdx.x;
    const float* src; u16* dst; int base;
    if      (bid < 8192) { src = x;      dst = x_bf;   base = bid; }
    else if (bid < 8448) { src = q_w;    dst = wq_bf;  base = bid - 8192; }
    else if (bid < 8960) { src = kv_w;   dst = wkv_bf; base = bid - 8448; }
    else if (bid < 9216) { src = sr_w;   dst = wsr_bf; base = bid - 8960; }
    else                 { src = proj_w; dst = wpr_bf; base = bid - 9216; }
    const int i = base * 256 + threadIdx.x;
    const float4 v = ((const float4*)src)[i];
    ushort4 o;
    o.x = f2bf(v.x); o.y = f2bf(v.y); o.z = f2bf(v.z); o.w = f2bf(v.w);
    ((ushort4*)dst)[i] = o;
}

// ---------------------------------------------------------------------------
// token2map pass 1: bucket tokens into per-cell slot lists (int atomics only)
// ---------------------------------------------------------------------------
__global__ __launch_bounds__(256) void scatter_idx_kernel(const float* __restrict__ loc,
    int* __restrict__ cnt_i, int* __restrict__ slots)
{
    const int token = blockIdx.x * 256 + threadIdx.x;     // 0..16383
    const int b = token >> 11;
    float lx = loc[token * 2 + 0];
    float ly = loc[token * 2 + 1];
    lx = fminf(fmaxf(lx, -1.0f), 1.0f);
    ly = fminf(fmaxf(ly, -1.0f), 1.0f);
    const float pxf = rintf(0.5f * (lx + 1.0f) * 32.0f - 0.5f);   // round-half-even
    const float pyf = rintf(0.5f * (ly + 1.0f) * 32.0f - 0.5f);
    int x0 = (int)pxf; x0 = min(max(x0, 0), 31);
    int y0 = (int)pyf; y0 = min(max(y0, 0), 31);
    const int row = b * GM + y0 * 32 + x0;
    const int slot = atomicAdd(&cnt_i[row], 1);
    if (slot < 128) slots[row * 128 + slot] = token;      // 128 >> max cell load (~62)
}

// ---------------------------------------------------------------------------
// token2map pass 2: gather-reduce + normalize, bf16 feat out + conf out.
// conf is pre-scaled by log2e (attention logits run in the exp2 domain).
// ---------------------------------------------------------------------------
__global__ __launch_bounds__(256) void gather_reduce_kernel(
    const float* __restrict__ x_source, const float* __restrict__ conf_src,
    const int* __restrict__ cnt_i, const int* __restrict__ slots,
    u16* __restrict__ featb, float* __restrict__ conf)
{
    const int row = blockIdx.x;            // 0..8191
    const int tid = threadIdx.x;
    const int n0 = cnt_i[row];
    const int n = min(n0, 128);

    float a0 = 0.0f, a1 = 0.0f;
    #pragma unroll 2
    for (int t = 0; t < n; ++t) {
        const int tok = slots[row * 128 + t];
        const float* s = x_source + (size_t)tok * CC;
        a0 += s[tid];
        a1 += s[tid + 256];
    }

    __shared__ float cred[2];
    float cv = (tid < n) ? conf_src[slots[row * 128 + tid]] : 0.0f;
    if (tid < 128) {
        #pragma unroll
        for (int o = 32; o > 0; o >>= 1) cv += __shfl_down(cv, o, 64);
        if ((tid & 63) == 0) cred[tid >> 6] = cv;
    }
    __syncthreads();

    const float fn = (float)n0;
    const float sc = (n0 > 0) ? (1.0f / (fn + 1e-6f)) : 0.0f;
    u16* o = featb + (size_t)row * CC;
    o[tid]       = f2bf(a0 * sc);
    o[tid + 256] = f2bf(a1 * sc);
    if (tid == 0) conf[row] = (cred[0] + cred[1]) * sc * LOG2E;
}

// ---------------------------------------------------------------------------
// bf16 MFMA GEMM body: C[M][Nn] = A[M][K] @ Bw[Nn][K]^T (+bias).
// 128x128 tile, BK=32, 4 waves (2x2), global_load_lds w=16, XOR-swizzled LDS,
// DOUBLE-BUFFERED: stage kt+1 before computing kt, ONE barrier per tile.
// OUTMODE: 0 = fp32 out, 2 = V^T key-permuted scatter-out,
//          3 = bf16 out scaled QSCALE (attention Q pre-scale, exp2 domain),
//          4 = K MFMA-A-fragment scatter-out [bh][kt][ks][jt][lane][8].
// ---------------------------------------------------------------------------
template<bool BIAS, int OUTMODE>
__device__ __forceinline__ void gemm_body(int bx, int by,
    const u16* __restrict__ A, const u16* __restrict__ Bw,
    const float* __restrict__ bias,
    float* __restrict__ Cf, u16* __restrict__ Cb, u16* __restrict__ Vt,
    int M, int Nn, int K, u16* sm)
{
    u16* As = sm;            // [2][4096]
    u16* Bs = sm + 8192;     // [2][4096]
    const int tid = threadIdx.x;
    const int l = tid & 63, r = l & 15, g = l >> 4;
    const int w = tid >> 6, wm = w >> 1, wn = w & 1;
    const int m0 = by * 128, n0 = bx * 128;

    f32x4 acc[4][4] = {};
    const int nkt = K >> 5;

    // prologue: stage kt=0 into buffer 0
    #pragma unroll
    for (int it = 0; it < 2; ++it) {
        const int c = it * 256 + tid;
        const int row = c >> 2;
        const int gg = (c & 3) ^ ((row >> 2) & 3);
        __builtin_amdgcn_global_load_lds(A  + (size_t)(m0 + row) * K + gg * 8,
            (u16*)((char*)As + it * 4096 + (tid & 192) * 16), 16, 0, 0);
        __builtin_amdgcn_global_load_lds(Bw + (size_t)(n0 + row) * K + gg * 8,
            (u16*)((char*)Bs + it * 4096 + (tid & 192) * 16), 16, 0, 0);
    }
    __syncthreads();

    for (int kt = 0; kt < nkt; ++kt) {
        const int cur = kt & 1;
        if (kt + 1 < nkt) {
            #pragma unroll
            for (int it = 0; it < 2; ++it) {
                const int c = it * 256 + tid;
                const int row = c >> 2;
                const int gg = (c & 3) ^ ((row >> 2) & 3);
                __builtin_amdgcn_global_load_lds(A  + (size_t)(m0 + row) * K + (kt + 1) * 32 + gg * 8,
                    (u16*)((char*)As + (cur ^ 1) * 8192 + it * 4096 + (tid & 192) * 16), 16, 0, 0);
                __builtin_amdgcn_global_load_lds(Bw + (size_t)(n0 + row) * K + (kt + 1) * 32 + gg * 8,
                    (u16*)((char*)Bs + (cur ^ 1) * 8192 + it * 4096 + (tid & 192) * 16), 16, 0, 0);
            }
        }

        short8 af[4], bf[4];
        #pragma unroll
        for (int mi = 0; mi < 4; ++mi) {
            const int row = wm * 64 + mi * 16 + r;
            af[mi] = *(const short8*)((char*)As + cur * 8192 + row * 64 + ((g ^ (r >> 2)) & 3) * 16);
        }
        #pragma unroll
        for (int ni = 0; ni < 4; ++ni) {
            const int row = wn * 64 + ni * 16 + r;
            bf[ni] = *(const short8*)((char*)Bs + cur * 8192 + row * 64 + ((g ^ (r >> 2)) & 3) * 16);
        }
        #pragma unroll
        for (int mi = 0; mi < 4; ++mi)
            #pragma unroll
            for (int ni = 0; ni < 4; ++ni)
                acc[mi][ni] = __builtin_amdgcn_mfma_f32_16x16x32_bf16(af[mi], bf[ni], acc[mi][ni], 0, 0, 0);

        __syncthreads();   // drains next-stage loads + fences LDS reuse
    }

    #pragma unroll
    for (int mi = 0; mi < 4; ++mi) {
        const int rbase = m0 + wm * 64 + mi * 16 + g * 4;   // C/D: row=(l>>4)*4+reg
        #pragma unroll
        for (int ni = 0; ni < 4; ++ni) {
            const int col = n0 + wn * 64 + ni * 16 + r;     // C/D: col=lane&15
            const float bv = BIAS ? bias[col] : 0.0f;
            #pragma unroll
            for (int reg = 0; reg < 4; ++reg) {
                const float v = acc[mi][ni][reg] + bv;
                if (OUTMODE == 0) {
                    Cf[(size_t)(rbase + reg) * Nn + col] = v;
                } else if (OUTMODE == 3) {
                    Cb[(size_t)(rbase + reg) * Nn + col] = f2bf(v * QSCALE);
                } else if (OUTMODE == 2) {
                    // V^T: rows = V features, cols = tokens; key axis permuted so
                    // attention's packed-P A-fragment lines up slot-for-slot.
                    const int f = rbase + reg;              // V feature 0..511
                    const int head = f >> 6, d = f & 63;
                    const int bb2 = col >> 10, tok = col & 1023;
                    const int u = tok & 63;
                    const int S = ((u >> 5) << 5) | (((u >> 2) & 3) << 3)
                                | (((u >> 4) & 1) << 2) | (u & 3);
                    const int stok = (tok & ~63) | S;
                    Vt[(((size_t)bb2 * 8 + head) * 64 + d) * 1024 + stok] = f2bf(v);
                } else {
                    // K MFMA-A-fragment layout: [bh][kt][ks][jt][lane=gg*16+rr][e]
                    const int f = col;                      // K feature 0..511
                    const int hh = f >> 6, d = f & 63;
                    const int kks = d >> 5, gg = (d >> 3) & 3, e = d & 7;
                    const int t = rbase + reg;              // token 0..8191
                    const int bb2 = t >> 10, tok = t & 1023;
                    const int ktt = tok >> 6, key = tok & 63;
                    const int jtt = key >> 4, rr = key & 15;
                    Vt[(((((size_t)(bb2 * 8 + hh) * 16 + ktt) * 2 + kks) * 4 + jtt) * 64
                        + (gg * 16 + rr)) * 8 + e] = f2bf(v);
                }
            }
        }
    }
}

// standalone GEMM (sr, proj)
template<bool BIAS, int OUTMODE>
__global__ __launch_bounds__(256) void gemm_single(const u16* __restrict__ A,
    const u16* __restrict__ Bw, const float* __restrict__ bias,
    float* __restrict__ Cf, u16* __restrict__ Cb, u16* __restrict__ Vt,
    int M, int Nn, int K)
{
    __shared__ u16 sm[16384];
    gemm_body<BIAS, OUTMODE>(blockIdx.x, blockIdx.y, A, Bw, bias, Cf, Cb, Vt, M, Nn, K, sm);
}

// fused K + V^T + Q GEMMs (all inputs ready after ln_gelu): 1024 blocks
__global__ __launch_bounds__(256) void gemm_kvq_kernel(
    const u16* __restrict__ xs_bf, const u16* __restrict__ wkv_bf,
    u16* __restrict__ kf_bf, u16* __restrict__ vt_bf,
    const u16* __restrict__ x_bf, const u16* __restrict__ wq_bf,
    u16* __restrict__ q_bf)
{
    __shared__ u16 sm[16384];
    const int bid = blockIdx.x;
    if (bid < 256) {
        // K = xs @ Wk^T -> MFMA-A-fragment layout (M=8192, N=512)
        gemm_body<false, 4>(bid & 3, bid >> 2, xs_bf, wkv_bf, nullptr,
                            nullptr, nullptr, kf_bf, 8192, 512, 512, sm);
    } else if (bid < 512) {
        // V^T = Wv @ xs^T (M=512, N=8192), key-permuted transposed write
        const int id = bid - 256;
        gemm_body<false, 2>(id & 63, id >> 6, wkv_bf + (size_t)512 * 512, xs_bf, nullptr,
                            nullptr, nullptr, vt_bf, 512, 8192, 512, sm);
    } else {
        // q = (x @ q_w^T) * QSCALE   (M=16384, N=512)
        const int id = bid - 512;
        gemm_body<false, 3>(id & 3, id >> 2, x_bf, wq_bf, nullptr,
                            nullptr, q_bf, nullptr, 16384, 512, 512, sm);
    }
}

// ---------------------------------------------------------------------------
// LayerNorm + exact GELU (fp32 in, bf16 out), one block per row of 512
// ---------------------------------------------------------------------------
__global__ __launch_bounds__(256) void ln_gelu_kernel(const float* __restrict__ xs,
    u16* __restrict__ xsb, const float* __restrict__ g, const float* __restrict__ bta)
{
    const int row = blockIdx.x;
    const int tid = threadIdx.x;
    const float2 v = *(const float2*)&xs[(size_t)row * CC + tid * 2];
    float s  = v.x + v.y;
    float ss = v.x * v.x + v.y * v.y;
    #pragma unroll
    for (int o = 32; o > 0; o >>= 1) { s += __shfl_down(s, o); ss += __shfl_down(ss, o); }
    __shared__ float red[10];
    const int wid = tid >> 6;
    if ((tid & 63) == 0) { red[wid] = s; red[4 + wid] = ss; }
    __syncthreads();
    if (tid == 0) {
        const float S  = red[0] + red[1] + red[2] + red[3];
        const float SS = red[4] + red[5] + red[6] + red[7];
        const float mu = S * (1.0f / 512.0f);
        const float var = SS * (1.0f / 512.0f) - mu * mu;
        red[8] = mu;
        red[9] = 1.0f / sqrtf(var + 1e-5f);
    }
    __syncthreads();
    const float mu = red[8], inv = red[9];
    const float2 gg = *(const float2*)&g[tid * 2];
    const float2 bb = *(const float2*)&bta[tid * 2];
    float x0 = (v.x - mu) * inv * gg.x + bb.x;
    float x1 = (v.y - mu) * inv * gg.y + bb.y;
    x0 = 0.5f * x0 * (1.0f + erff(x0 * 0.70710678118654752f));
    x1 = 0.5f * x1 * (1.0f + erff(x1 * 0.70710678118654752f));
    ushort2 o; o.x = f2bf(x0); o.y = f2bf(x1);
    *(ushort2*)&xsb[(size_t)row * CC + tid * 2] = o;
}

// ---------------------------------------------------------------------------
// MFMA flash attention v6: ZERO LDS, ZERO barriers. K is pre-packed in MFMA
// A-fragment order by the K-GEMM -> coalesced 16B/lane L2 loads; V^T key-
// permuted; conf lane-broadcast f32x4 from L2. All waves fully independent;
// softmax in exp2 domain (q pre-scaled 0.125*log2e, conf pre-scaled log2e).
// QBLK=128 (two 16-row Q halves per wave), XCD-swizzled grid.
// ---------------------------------------------------------------------------
__global__ __launch_bounds__(256) void attn_mfma(const u16* __restrict__ q,
    const u16* __restrict__ kf, const u16* __restrict__ vt,
    const float* __restrict__ conf, u16* __restrict__ out)
{
    const int bid = blockIdx.x;             // 0..1023
    const int xcd = bid & 7, slot = bid >> 3;
    const int bh = xcd * 8 + (slot & 7);    // 8 bh per XCD -> K+V^T L2-resident
    const int qt = slot >> 3;               // 0..15
    const int b = bh >> 3, h = bh & 7;
    const int tid = threadIdx.x;
    const int l = tid & 63, r = l & 15, g = l >> 4;
    const int w = tid >> 6;

    short8 qa[2], qb_[2];
    {
        const u16* qp = q + ((size_t)(b * NN + qt * 128 + w * 32 + r)) * CC + h * HD + g * 8;
        qa[0]  = *(const short8*)(qp);
        qa[1]  = *(const short8*)(qp + 32);
        qb_[0] = *(const short8*)(qp + 16 * CC);
        qb_[1] = *(const short8*)(qp + 16 * CC + 32);
    }

    const u16* kfb   = kf + (size_t)(b * 8 + h) * 65536;   // [kt][ks][jt][lane][8]
    const u16* vbase = vt + (size_t)(b * 8 + h) * 65536;   // [d][keyslot]
    const float* confp = conf + b * GM;

    f32x4 oa[4] = {}, ob[4] = {};
    float ma = -1e30f, la = 0.0f, mb = -1e30f, lb = 0.0f;

    #pragma unroll 1
    for (int kt = 0; kt < 16; ++kt) {
        // ---- swapped QK^T from fragment-packed K (coalesced L2 loads) ----
        f32x4 sa[4] = {}, sb[4] = {};
        #pragma unroll
        for (int ks = 0; ks < 2; ++ks) {
            short8 kfr[4];
            #pragma unroll
            for (int jt = 0; jt < 4; ++jt)
                kfr[jt] = *(const short8*)(kfb + (((kt * 2 + ks) * 4 + jt) << 9) + l * 8);
            #pragma unroll
            for (int jt = 0; jt < 4; ++jt) {
                sa[jt] = __builtin_amdgcn_mfma_f32_16x16x32_bf16(kfr[jt], qa[ks],  sa[jt], 0, 0, 0);
                sb[jt] = __builtin_amdgcn_mfma_f32_16x16x32_bf16(kfr[jt], qb_[ks], sb[jt], 0, 0, 0);
            }
        }

        // ---- lane-local online softmax (exp2 domain) ----
        float tma = -1e30f, tmb = -1e30f;
        #pragma unroll
        for (int jt = 0; jt < 4; ++jt) {
            const f32x4 cf = *(const f32x4*)(confp + kt * 64 + jt * 16 + g * 4);
            #pragma unroll
            for (int reg = 0; reg < 4; ++reg) {
                sa[jt][reg] += cf[reg];
                sb[jt][reg] += cf[reg];
                tma = fmaxf(tma, sa[jt][reg]);
                tmb = fmaxf(tmb, sb[jt][reg]);
            }
        }
        tma = fmaxf(tma, __shfl_xor(tma, 16, 64));
        tma = fmaxf(tma, __shfl_xor(tma, 32, 64));
        tmb = fmaxf(tmb, __shfl_xor(tmb, 16, 64));
        tmb = fmaxf(tmb, __shfl_xor(tmb, 32, 64));

        const float mta = fmaxf(ma, tma);
        const float mtb = fmaxf(mb, tmb);
        const float rfa = __builtin_amdgcn_exp2f(ma - mta);
        const float rfb = __builtin_amdgcn_exp2f(mb - mtb);
        ma = mta; mb = mtb;

        float psa = 0.0f, psb = 0.0f;
        #pragma unroll
        for (int jt = 0; jt < 4; ++jt)
            #pragma unroll
            for (int reg = 0; reg < 4; ++reg) {
                const float eva = __builtin_amdgcn_exp2f(sa[jt][reg] - ma);
                const float evb = __builtin_amdgcn_exp2f(sb[jt][reg] - mb);
                sa[jt][reg] = eva; sb[jt][reg] = evb;
                psa += eva; psb += evb;
            }
        psa += __shfl_xor(psa, 16, 64);
        psa += __shfl_xor(psa, 32, 64);
        psb += __shfl_xor(psb, 16, 64);
        psb += __shfl_xor(psb, 32, 64);
        la = la * rfa + psa;
        lb = lb * rfb + psb;

        // pack P (bf16 pairs)
        unsigned wa[4][2], wb[4][2];
        #pragma unroll
        for (int jt = 0; jt < 4; ++jt) {
            wa[jt][0] = cvt_pk_bf16(sa[jt][0], sa[jt][1]);
            wa[jt][1] = cvt_pk_bf16(sa[jt][2], sa[jt][3]);
            wb[jt][0] = cvt_pk_bf16(sb[jt][0], sb[jt][1]);
            wb[jt][1] = cvt_pk_bf16(sb[jt][2], sb[jt][3]);
        }

        // rescale O (rows q=4g+reg; rf lives at lane q)
        float rfqa[4], rfqb[4];
        #pragma unroll
        for (int reg = 0; reg < 4; ++reg) {
            rfqa[reg] = __shfl(rfa, g * 4 + reg, 64);
            rfqb[reg] = __shfl(rfb, g * 4 + reg, 64);
        }
        #pragma unroll
        for (int ni = 0; ni < 4; ++ni)
            #pragma unroll
            for (int reg = 0; reg < 4; ++reg) {
                oa[ni][reg] *= rfqa[reg];
                ob[ni][reg] *= rfqb[reg];
            }

        // ---- PV: V^T fragments from L2, packed P as A-operand ----
        #pragma unroll
        for (int ks = 0; ks < 2; ++ks) {
            short8 vfr[4];
            #pragma unroll
            for (int ni = 0; ni < 4; ++ni)
                vfr[ni] = *(const short8*)(vbase + (size_t)(ni * 16 + r) * 1024
                                           + kt * 64 + ks * 32 + g * 8);
            i32x4 pwa, pwb;
            pwa.x = (int)wa[2 * ks][0];     pwa.y = (int)wa[2 * ks][1];
            pwa.z = (int)wa[2 * ks + 1][0]; pwa.w = (int)wa[2 * ks + 1][1];
            pwb.x = (int)wb[2 * ks][0];     pwb.y = (int)wb[2 * ks][1];
            pwb.z = (int)wb[2 * ks + 1][0]; pwb.w = (int)wb[2 * ks + 1][1];
            const short8 paa = __builtin_bit_cast(short8, pwa);
            const short8 pab = __builtin_bit_cast(short8, pwb);
            #pragma unroll
            for (int ni = 0; ni < 4; ++ni) {
                oa[ni] = __builtin_amdgcn_mfma_f32_16x16x32_bf16(paa, vfr[ni], oa[ni], 0, 0, 0);
                ob[ni] = __builtin_amdgcn_mfma_f32_16x16x32_bf16(pab, vfr[ni], ob[ni], 0, 0, 0);
            }
        }
    }

    // epilogue: divide by l (stats live at lane q) and store bf16
    float lqa[4], lqb[4];
    #pragma unroll
    for (int reg = 0; reg < 4; ++reg) {
        lqa[reg] = __shfl(la, g * 4 + reg, 64);
        lqb[reg] = __shfl(lb, g * 4 + reg, 64);
    }
    const size_t orowa = (size_t)(b * NN + qt * 128 + w * 32 + g * 4);
    #pragma unroll
    for (int ni = 0; ni < 4; ++ni)
        #pragma unroll
        for (int reg = 0; reg < 4; ++reg) {
            out[(orowa + reg) * CC + h * HD + ni * 16 + r]      = f2bf(oa[ni][reg] / lqa[reg]);
            out[(orowa + 16 + reg) * CC + h * HD + ni * 16 + r] = f2bf(ob[ni][reg] / lqb[reg]);
        }
}

// ---------------------------------------------------------------------------
extern "C" void kernel_launch(void* const* d_in, const int* in_sizes, int n_in,
                              void* d_out, int out_size, void* d_ws, size_t ws_size,
                              hipStream_t stream)
{
    (void)in_sizes; (void)n_in; (void)out_size; (void)ws_size;
    const float* x        = (const float*)d_in[0];
    const float* x_source = (const float*)d_in[1];
    const float* loc      = (const float*)d_in[2];
    const float* conf_src = (const float*)d_in[3];
    const float* q_w      = (const float*)d_in[4];
    const float* kv_w     = (const float*)d_in[5];
    const float* sr_w     = (const float*)d_in[6];
    const float* sr_b     = (const float*)d_in[7];
    const float* ln_g     = (const float*)d_in[8];
    const float* ln_b     = (const float*)d_in[9];
    const float* proj_w   = (const float*)d_in[10];
    const float* proj_b   = (const float*)d_in[11];

    char* ws = (char*)d_ws;
    int*   slots   = (int*)(ws + B_FEATF);    // 4MB, dead before attn_bf is written
    float* xs      = (float*)(ws + B_XSF);
    int*   cnt_i   = (int*)(ws + B_CNT);
    float* conf    = (float*)(ws + B_CONF);
    u16*   x_bf    = (u16*)(ws + B_XBF);
    u16*   kf_bf   = (u16*)(ws + B_KB);
    u16*   vt_bf   = (u16*)(ws + B_VT);
    u16*   feat_bf = (u16*)(ws + B_FEATBF);
    u16*   xs_bf   = (u16*)(ws + B_XSBF);
    u16*   wq_bf   = (u16*)(ws + B_WQ);
    u16*   wkv_bf  = (u16*)(ws + B_WKV);
    u16*   wsr_bf  = (u16*)(ws + B_WSR);
    u16*   wpr_bf  = (u16*)(ws + B_WPROJ);
    u16*   q_bf    = (u16*)(ws + B_XSF);      // reuse xs fp32 (dead after ln_gelu)
    u16*   attn_bf = (u16*)(ws + B_FEATF);    // reuse slots region (dead after gather)
    float* outp    = (float*)d_out;

    hipMemsetAsync(cnt_i, 0, 8192 * sizeof(int), stream);

    // all casts in one launch
    cast_all_kernel<<<9472, 256, 0, stream>>>(x, x_bf, q_w, wq_bf, kv_w, wkv_bf,
                                              sr_w, wsr_bf, proj_w, wpr_bf);

    // token2map: bucket + gather-reduce (writes bf16 feat + log2e-scaled conf)
    scatter_idx_kernel<<<64, 256, 0, stream>>>(loc, cnt_i, slots);
    gather_reduce_kernel<<<8192, 256, 0, stream>>>(x_source, conf_src, cnt_i, slots,
                                                   feat_bf, conf);

    // xs = feat @ sr_w^T + sr_b   (fp32 out for exact LN)
    gemm_single<true, 0><<<dim3(4, 64), 256, 0, stream>>>(feat_bf, wsr_bf, sr_b,
                                                          xs, nullptr, nullptr, 8192, 512, 512);
    ln_gelu_kernel<<<8192, 256, 0, stream>>>(xs, xs_bf, ln_g, ln_b);

    // K(fragments) + V^T + q in one launch (1024 blocks)
    gemm_kvq_kernel<<<1024, 256, 0, stream>>>(xs_bf, wkv_bf, kf_bf, vt_bf,
                                              x_bf, wq_bf, q_bf);

    // attention -> bf16 (into old slots region); XCD-swizzled 1-D grid
    attn_mfma<<<1024, 256, 0, stream>>>(q_bf, kf_bf, vt_bf, conf, attn_bf);

    // out = attn @ proj_w^T + proj_b  (fp32 out)
    gemm_single<true, 0><<<dim3(4, 128), 256, 0, stream>>>(attn_bf, wpr_bf, proj_b,
                                                           outp, nullptr, nullptr, 16384, 512, 512);
}